// Round 13
// baseline (242.454 us; speedup 1.0000x reference)
//
#include <hip/hip_runtime.h>

#define NROWS 65536
#define DIM   64
#define NE    512

// d_out is FLOAT32: [ z_q (4194304) | indices-as-float (65536) | loss (1) ]
// Scratch in d_ws (~142 KB used):
#define WS_PRESPLIT 0        // 512 rows x 256B: (-2e)_hi [0,128) | (-2e)_lo [128,256), NO swizzle
#define WS_PREY     131072   // 512 x 16B: (ynorm_hi, ynorm_lo, 0...)
#define WS_YNORM    139264   // 512 x f32 np-pairwise ||e||^2
#define WS_ACC      141312   // u64 fixed-point loss accumulator
#define WS_TICKET   141320   // u32 completion ticket

typedef __attribute__((ext_vector_type(8)))  short bf16x8;
typedef __attribute__((ext_vector_type(16))) float f32x16;

static __device__ __forceinline__ unsigned short bf16rne(float x) {
    unsigned int u = __float_as_uint(x);
    u += 0x7FFFu + ((u >> 16) & 1u);            // RNE (finite inputs only)
    return (unsigned short)(u >> 16);
}
static __device__ __forceinline__ float bf16tof(unsigned short h) {
    return __uint_as_float(((unsigned int)h) << 16);
}

// K0: codebook prep (512 rows, 2 blocks) + zero loss acc/ticket. No swizzle.
__global__ __launch_bounds__(256) void vq_prep(
    const float* __restrict__ ew, char* ws)
{
    const int r = blockIdx.x * 256 + threadIdx.x;     // 0..511
    if (r == 0) {
        *(unsigned long long*)(ws + WS_ACC)    = 0ull;
        *(unsigned long long*)(ws + WS_TICKET) = 0ull;
    }
    float a[64];
    const float4* src = (const float4*)(ew + (size_t)r * DIM);
    #pragma unroll
    for (int q = 0; q < 16; ++q) {
        float4 v = src[q];
        a[q*4+0]=v.x; a[q*4+1]=v.y; a[q*4+2]=v.z; a[q*4+3]=v.w;
    }
    // numpy-pairwise ||e||^2 (exact np f32 order)
    float rc[8];
    #pragma unroll
    for (int j = 0; j < 8; ++j) rc[j] = __fmul_rn(a[j], a[j]);
    #pragma unroll
    for (int i = 8; i < 64; i += 8)
        #pragma unroll
        for (int j = 0; j < 8; ++j)
            rc[j] = __fadd_rn(rc[j], __fmul_rn(a[i+j], a[i+j]));
    float Y = __fadd_rn(__fadd_rn(__fadd_rn(rc[0],rc[1]),__fadd_rn(rc[2],rc[3])),
                        __fadd_rn(__fadd_rn(rc[4],rc[5]),__fadd_rn(rc[6],rc[7])));
    ((float*)(ws + WS_YNORM))[r] = Y;
    unsigned short ynh = bf16rne(Y);
    unsigned short ynl = bf16rne(Y - bf16tof(ynh));
    bf16x8 py = {};
    py[0] = (short)ynh; py[1] = (short)ynl;
    *(bf16x8*)(ws + WS_PREY + r*16) = py;
    char* base = ws + WS_PRESPLIT + (size_t)r * 256;
    #pragma unroll
    for (int c = 0; c < 8; ++c) {
        bf16x8 h, l;
        #pragma unroll
        for (int j = 0; j < 8; ++j) {
            float x = -2.0f * a[c*8+j];
            unsigned short hb = bf16rne(x);
            h[j] = (short)hb;
            l[j] = (short)bf16rne(x - bf16tof(hb));
        }
        *(bf16x8*)(base + c*16)       = h;
        *(bf16x8*)(base + c*16 + 128) = l;
    }
}

// K1: 2048 blocks x 128 threads (2 waves). Block owns 32 z-rows; wave w ranks
// embed half [w*256,(w+1)*256) via MFMA with A-fragments loaded straight from
// the L2-resident split codebook (no LDS staging, no main-loop barriers).
// Cross-wave pool merge + near-tie rescan + index/z_q/loss epilogue.
__global__ __launch_bounds__(128, 4) void vq_fused(
    const float* __restrict__ z, const float* __restrict__ ew,
    char* ws, float* out)
{
    __shared__ float4 mrg[32];
    __shared__ int    rwin[32];
    __shared__ float  rdist[32];
    __shared__ float  rX[32];
    __shared__ float  zs[64];
    __shared__ float  rd2[2];
    __shared__ int    ri2[2];
    __shared__ unsigned int flagbits;

    const int tid  = threadIdx.x;
    const int lane = tid & 63;
    const int wv   = tid >> 6;      // 0,1: embed half
    const int hh   = lane >> 5;
    const int l31  = lane & 31;
    const int R0   = blockIdx.x * 32;
    const int zrow = R0 + l31;
    const int eoff = wv * 256;

    if (tid == 0) flagbits = 0u;

    // ---- z fragments (split-bf16) + f32 sum-sq; B: n=lane&31, k=8*hh+j ----
    bf16x8 zh[4], zl[4];
    float xacc = 0.f;
    {
        const float* zp = z + (size_t)zrow * DIM + hh * 8;
        #pragma unroll
        for (int kt = 0; kt < 4; ++kt) {
            float4 p0 = *(const float4*)(zp + kt*16);
            float4 p1 = *(const float4*)(zp + kt*16 + 4);
            float a[8] = {p0.x,p0.y,p0.z,p0.w,p1.x,p1.y,p1.z,p1.w};
            bf16x8 hv, lv;
            #pragma unroll
            for (int j = 0; j < 8; ++j) {
                unsigned short hb = bf16rne(a[j]);
                hv[j] = (short)hb;
                lv[j] = (short)bf16rne(a[j] - bf16tof(hb));
                xacc  = fmaf(a[j], a[j], xacc);
            }
            zh[kt] = hv; zl[kt] = lv;
        }
    }

    const bf16x8 zero8 = {};
    bf16x8 bones = {};
    if (hh == 0) { bones[0] = (short)0x3F80; bones[1] = (short)0x3F80; }

    float d1 = 3.4e38f, d2 = 3.4e38f;
    int   i1 = 0;

    // ---- main loop: 8 tiles of 32 embeds, fragments from L2 ----
    for (int t = 0; t < 8; ++t) {
        const int  e0    = eoff + t*32;
        const char* abase = ws + WS_PRESPLIT + (size_t)(e0 + l31) * 256;
        bf16x8 ah[4], al[4];
        #pragma unroll
        for (int kt = 0; kt < 4; ++kt) {
            ah[kt] = *(const bf16x8*)(abase + kt*32 + hh*16);
            al[kt] = *(const bf16x8*)(abase + kt*32 + hh*16 + 128);
        }
        bf16x8 ay = zero8;
        if (hh == 0)
            ay = *(const bf16x8*)(ws + WS_PREY + (size_t)(e0 + l31) * 16);

        f32x16 acc;
        #pragma unroll
        for (int g = 0; g < 16; ++g) acc[g] = 0.f;
        #pragma unroll
        for (int kt = 0; kt < 4; ++kt) {
            acc = __builtin_amdgcn_mfma_f32_32x32x16_bf16(ah[kt], zh[kt], acc, 0,0,0);
            acc = __builtin_amdgcn_mfma_f32_32x32x16_bf16(ah[kt], zl[kt], acc, 0,0,0);
            acc = __builtin_amdgcn_mfma_f32_32x32x16_bf16(al[kt], zh[kt], acc, 0,0,0);
        }
        acc = __builtin_amdgcn_mfma_f32_32x32x16_bf16(ay, bones, acc, 0,0,0);

        const int ebase = e0 + 4*hh;
        #pragma unroll
        for (int g = 0; g < 16; ++g) {
            float d = acc[g];                 // ynorm[e] - 2 z.e (approx)
            int   e = ebase + (g & 3) + 8*(g >> 2);
            d2 = fminf(fmaxf(d, d1), d2);
            bool bt = d < d1;
            i1 = bt ? e : i1;
            d1 = fminf(d, d1);
        }
    }

    // ---- intra-wave hh merge ----
    float od1 = __shfl_xor(d1, 32, 64);
    int   oi1 = __shfl_xor(i1, 32, 64);
    float od2 = __shfl_xor(d2, 32, 64);
    bool  oth = (od1 < d1) || (od1 == d1 && oi1 < i1);
    int   wiw = oth ? oi1 : i1;
    float s1w = fminf(d1, od1);
    float s2w = fminf(fmaxf(d1, od1), fminf(d2, od2));
    float X   = xacc + __shfl_xor(xacc, 32, 64);

    // ---- cross-wave merge via LDS ----
    if (wv == 1 && hh == 0)
        mrg[l31] = make_float4(s1w, __int_as_float(wiw), s2w, 0.f);
    __syncthreads();
    if (wv == 0 && hh == 0) {
        float4 b = mrg[l31];
        float s1b = b.x, s2b = b.z;
        int   ib  = __float_as_int(b.y);
        bool  tA  = (s1w <= s1b);           // tie -> wave0 = lower index
        int   wi  = tA ? wiw : ib;
        float s1  = fminf(s1w, s1b);
        float s2  = fminf(fmaxf(s1w, s1b), fminf(s2w, s2b));
        float Xs  = X + 1e-3f;
        float ue  = __uint_as_float(__float_as_uint(Xs) & 0x7F800000u) * 1.1920929e-7f;
        bool  flag = (s2 - s1) < (2.0f * ue + 2e-6f);
        rwin[l31]  = wi;
        rdist[l31] = s1;
        rX[l31]    = X;
        if (flag) atomicOr(&flagbits, 1u << l31);
        out[(size_t)NROWS*DIM + R0 + l31] = (float)wi;
    }
    __syncthreads();

    // ---- rescan flagged rows (np-f32 exact; block-parallel, 4 embeds/thread) ----
    unsigned bits = flagbits;
    const float* yn = (const float*)(ws + WS_YNORM);
    while (bits) {
        int r = __ffs(bits) - 1;
        bits &= bits - 1;
        if (tid < 16)
            *(float4*)(zs + tid*4) = *(const float4*)(z + (size_t)(R0 + r) * DIM + tid*4);
        __syncthreads();
        float rc[8];
        #pragma unroll
        for (int j = 0; j < 8; ++j) rc[j] = __fmul_rn(zs[j], zs[j]);
        #pragma unroll
        for (int i = 8; i < 64; i += 8)
            #pragma unroll
            for (int j = 0; j < 8; ++j)
                rc[j] = __fadd_rn(rc[j], __fmul_rn(zs[i+j], zs[i+j]));
        float xn = __fadd_rn(__fadd_rn(__fadd_rn(rc[0],rc[1]),__fadd_rn(rc[2],rc[3])),
                             __fadd_rn(__fadd_rn(rc[4],rc[5]),__fadd_rn(rc[6],rc[7])));
        float bd = 3.4e38f; int bi = NE;
        #pragma unroll
        for (int k = 0; k < 4; ++k) {
            int e = tid + 128 * k;
            const float* ep = ew + (size_t)e * DIM;
            double m0 = 0.0, m1 = 0.0, m2 = 0.0, m3 = 0.0;
            #pragma unroll
            for (int q = 0; q < 16; ++q) {
                float4 ev = *(const float4*)(ep + q*4);
                m0 = fma((double)zs[q*4+0], (double)ev.x, m0);
                m1 = fma((double)zs[q*4+1], (double)ev.y, m1);
                m2 = fma((double)zs[q*4+2], (double)ev.z, m2);
                m3 = fma((double)zs[q*4+3], (double)ev.w, m3);
            }
            double m = (m0 + m1) + (m2 + m3);
            float W = __fadd_rn(xn, yn[e]);
            float d = __fadd_rn(W, -(2.0f * (float)m));
            if (d < bd || (d == bd && e < bi)) { bd = d; bi = e; }
        }
        #pragma unroll
        for (int off = 32; off >= 1; off >>= 1) {
            float od = __shfl_xor(bd, off, 64);
            int   oi = __shfl_xor(bi, off, 64);
            if (od < bd || (od == bd && oi < bi)) { bd = od; bi = oi; }
        }
        if (lane == 0) { rd2[wv] = bd; ri2[wv] = bi; }
        __syncthreads();
        if (tid == 0) {
            float fd = rd2[0]; int fi = ri2[0];
            if (rd2[1] < fd || (rd2[1] == fd && ri2[1] < fi)) { fd = rd2[1]; fi = ri2[1]; }
            rwin[r]  = fi;
            rdist[r] = fd;     // full np distance (includes X)
            rX[r]    = 0.f;    // no double count
            out[(size_t)NROWS*DIM + R0 + r] = (float)fi;
        }
        __syncthreads();
    }

    // ---- z_q write: 32 rows x 16 float4 = 512 float4 over 128 threads ----
    #pragma unroll
    for (int i = 0; i < 4; ++i) {
        int f4  = tid + 128 * i;          // 0..511
        int row = f4 >> 4;                // 0..31
        int c4  = f4 & 15;
        float4 v = *(const float4*)(ew + (size_t)rwin[row] * DIM + c4 * 4);
        *(float4*)(out + (size_t)R0 * DIM + (size_t)f4 * 4) = v;
    }

    // ---- loss: term = X + d per row; fixed-point u64 atomic + ticket ----
    float term = (tid < 32) ? (rX[tid] + rdist[tid]) : 0.f;
    #pragma unroll
    for (int off = 32; off >= 1; off >>= 1) term += __shfl_xor(term, off, 64);
    if (tid == 0) {
        unsigned long long q =
            (unsigned long long)((double)term * 268435456.0 + 0.5);
        atomicAdd((unsigned long long*)(ws + WS_ACC), q);
        __threadfence();
        unsigned int tk = atomicAdd((unsigned int*)(ws + WS_TICKET), 1u);
        if (tk == 2047u) {
            unsigned long long tot =
                atomicAdd((unsigned long long*)(ws + WS_ACC), 0ull);
            out[(size_t)NROWS*DIM + NROWS] =
                (float)(0.25 * ((double)tot / 268435456.0)
                        / (double)((size_t)NROWS * DIM));
        }
    }
}

extern "C" void kernel_launch(void* const* d_in, const int* in_sizes, int n_in,
                              void* d_out, int out_size, void* d_ws, size_t ws_size,
                              hipStream_t stream) {
    const float* z  = (const float*)d_in[0];
    const float* ew = (const float*)d_in[1];
    float* out = (float*)d_out;
    char*  ws  = (char*)d_ws;    // ~142 KB used; every byte rewritten each call
    vq_prep <<<2,    256, 0, stream>>>(ew, ws);
    vq_fused<<<2048, 128, 0, stream>>>(z, ew, ws, out);
}

// Round 14
// 203.075 us; speedup vs baseline: 1.1939x; 1.1939x over previous
//
#include <hip/hip_runtime.h>

#define NROWS 65536
#define DIM   64
#define NE    512

// d_out is FLOAT32: [ z_q (4194304) | indices-as-float (65536) | loss (1) ]
// Scratch in d_ws (~142 KB used):
#define WS_PRESPLIT 0        // 512 rows x 256B: (-2e)_hi [0,128) | (-2e)_lo [128,256)
#define WS_PREY     131072   // 512 x 16B: (ynorm_hi, ynorm_lo, 0...)
#define WS_YNORM    139264   // 512 x f32 np-pairwise ||e||^2
#define WS_ACC      141312   // u64 fixed-point loss accumulator
#define WS_TICKET   141320   // u32 completion ticket

typedef __attribute__((ext_vector_type(8)))  short bf16x8;
typedef __attribute__((ext_vector_type(16))) float f32x16;

static __device__ __forceinline__ unsigned short bf16rne(float x) {
    unsigned int u = __float_as_uint(x);
    u += 0x7FFFu + ((u >> 16) & 1u);            // RNE (finite inputs only)
    return (unsigned short)(u >> 16);
}
static __device__ __forceinline__ float bf16tof(unsigned short h) {
    return __uint_as_float(((unsigned int)h) << 16);
}

// K0: codebook prep (512 rows, 2 blocks) + zero loss acc/ticket.
__global__ __launch_bounds__(256) void vq_prep(
    const float* __restrict__ ew, char* ws)
{
    const int r = blockIdx.x * 256 + threadIdx.x;     // 0..511
    if (r == 0) {
        *(unsigned long long*)(ws + WS_ACC)    = 0ull;
        *(unsigned long long*)(ws + WS_TICKET) = 0ull;
    }
    float a[64];
    const float4* src = (const float4*)(ew + (size_t)r * DIM);
    #pragma unroll
    for (int q = 0; q < 16; ++q) {
        float4 v = src[q];
        a[q*4+0]=v.x; a[q*4+1]=v.y; a[q*4+2]=v.z; a[q*4+3]=v.w;
    }
    // numpy-pairwise ||e||^2 (exact np f32 order)
    float rc[8];
    #pragma unroll
    for (int j = 0; j < 8; ++j) rc[j] = __fmul_rn(a[j], a[j]);
    #pragma unroll
    for (int i = 8; i < 64; i += 8)
        #pragma unroll
        for (int j = 0; j < 8; ++j)
            rc[j] = __fadd_rn(rc[j], __fmul_rn(a[i+j], a[i+j]));
    float Y = __fadd_rn(__fadd_rn(__fadd_rn(rc[0],rc[1]),__fadd_rn(rc[2],rc[3])),
                        __fadd_rn(__fadd_rn(rc[4],rc[5]),__fadd_rn(rc[6],rc[7])));
    ((float*)(ws + WS_YNORM))[r] = Y;
    unsigned short ynh = bf16rne(Y);
    unsigned short ynl = bf16rne(Y - bf16tof(ynh));
    bf16x8 py = {};
    py[0] = (short)ynh; py[1] = (short)ynl;
    *(bf16x8*)(ws + WS_PREY + r*16) = py;
    char* base = ws + WS_PRESPLIT + (size_t)r * 256;
    #pragma unroll
    for (int c = 0; c < 8; ++c) {
        bf16x8 h, l;
        #pragma unroll
        for (int j = 0; j < 8; ++j) {
            float x = -2.0f * a[c*8+j];
            unsigned short hb = bf16rne(x);
            h[j] = (short)hb;
            l[j] = (short)bf16rne(x - bf16tof(hb));
        }
        *(bf16x8*)(base + c*16)       = h;
        *(bf16x8*)(base + c*16 + 128) = l;
    }
}

// K1: 2048 blocks x 128 threads (2 waves). Block owns 32 z-rows; wave wv ranks
// embed half [wv*256,(wv+1)*256) via MFMA, A-fragments streamed from the
// L2-resident split codebook. Cross-wave merge + rescan + write + loss.
__global__ __launch_bounds__(128, 2) void vq_fused(
    const float* __restrict__ z, const float* __restrict__ ew,
    char* ws, float* out)
{
    __shared__ float4 mrg[32];
    __shared__ int    rwin[32];
    __shared__ float  rdist[32];
    __shared__ float  rX[32];
    __shared__ float  zs[64];
    __shared__ float  rd2[2];
    __shared__ int    ri2[2];
    __shared__ unsigned int flagbits;

    const int tid  = threadIdx.x;
    const int lane = tid & 63;
    const int wv   = tid >> 6;      // 0,1: embed half
    const int hh   = lane >> 5;
    const int l31  = lane & 31;
    const int R0   = blockIdx.x * 32;
    const int zrow = R0 + l31;
    const int eoff = wv * 256;

    if (tid == 0) flagbits = 0u;

    // ---- z fragments (split-bf16) + f32 sum-sq; B: n=lane&31, k=8*hh+j ----
    bf16x8 zh[4], zl[4];
    float xacc = 0.f;
    {
        const float* zp = z + (size_t)zrow * DIM + hh * 8;
        #pragma unroll
        for (int kt = 0; kt < 4; ++kt) {
            float4 p0 = *(const float4*)(zp + kt*16);
            float4 p1 = *(const float4*)(zp + kt*16 + 4);
            float a[8] = {p0.x,p0.y,p0.z,p0.w,p1.x,p1.y,p1.z,p1.w};
            bf16x8 hv, lv;
            #pragma unroll
            for (int j = 0; j < 8; ++j) {
                unsigned short hb = bf16rne(a[j]);
                hv[j] = (short)hb;
                lv[j] = (short)bf16rne(a[j] - bf16tof(hb));
                xacc  = fmaf(a[j], a[j], xacc);
            }
            zh[kt] = hv; zl[kt] = lv;
        }
    }

    const bf16x8 zero8 = {};
    bf16x8 bones = {};
    if (hh == 0) { bones[0] = (short)0x3F80; bones[1] = (short)0x3F80; }

    float d1 = 3.4e38f, d2 = 3.4e38f;
    int   i1 = 0;

    // ---- main loop: 8 tiles of 32 embeds; per-kt fragment loads (low VGPR) ----
    for (int t = 0; t < 8; ++t) {
        const int   e0    = eoff + t*32;
        const char* abase = ws + WS_PRESPLIT + (size_t)(e0 + l31) * 256 + hh*16;

        f32x16 acc;
        #pragma unroll
        for (int g = 0; g < 16; ++g) acc[g] = 0.f;

        bf16x8 ay = zero8;
        if (hh == 0)
            ay = *(const bf16x8*)(ws + WS_PREY + (size_t)(e0 + l31) * 16);
        acc = __builtin_amdgcn_mfma_f32_32x32x16_bf16(ay, bones, acc, 0,0,0);

        #pragma unroll
        for (int kt = 0; kt < 4; ++kt) {
            bf16x8 ah = *(const bf16x8*)(abase + kt*32);
            bf16x8 al = *(const bf16x8*)(abase + kt*32 + 128);
            acc = __builtin_amdgcn_mfma_f32_32x32x16_bf16(ah, zh[kt], acc, 0,0,0);
            acc = __builtin_amdgcn_mfma_f32_32x32x16_bf16(ah, zl[kt], acc, 0,0,0);
            acc = __builtin_amdgcn_mfma_f32_32x32x16_bf16(al, zh[kt], acc, 0,0,0);
        }

        const int ebase = e0 + 4*hh;
        #pragma unroll
        for (int g = 0; g < 16; ++g) {
            float d = acc[g];                 // ynorm[e] - 2 z.e (approx)
            int   e = ebase + (g & 3) + 8*(g >> 2);
            d2 = fminf(fmaxf(d, d1), d2);
            bool bt = d < d1;
            i1 = bt ? e : i1;
            d1 = fminf(d, d1);
        }
    }

    // ---- intra-wave hh merge ----
    float od1 = __shfl_xor(d1, 32, 64);
    int   oi1 = __shfl_xor(i1, 32, 64);
    float od2 = __shfl_xor(d2, 32, 64);
    bool  oth = (od1 < d1) || (od1 == d1 && oi1 < i1);
    int   wiw = oth ? oi1 : i1;
    float s1w = fminf(d1, od1);
    float s2w = fminf(fmaxf(d1, od1), fminf(d2, od2));
    float X   = xacc + __shfl_xor(xacc, 32, 64);

    // ---- cross-wave merge via LDS ----
    if (wv == 1 && hh == 0)
        mrg[l31] = make_float4(s1w, __int_as_float(wiw), s2w, 0.f);
    __syncthreads();
    if (wv == 0 && hh == 0) {
        float4 b = mrg[l31];
        float s1b = b.x, s2b = b.z;
        int   ib  = __float_as_int(b.y);
        bool  tA  = (s1w <= s1b);           // tie -> wave0 = lower index
        int   wi  = tA ? wiw : ib;
        float s1  = fminf(s1w, s1b);
        float s2  = fminf(fmaxf(s1w, s1b), fminf(s2w, s2b));
        float Xs  = X + 1e-3f;
        float ue  = __uint_as_float(__float_as_uint(Xs) & 0x7F800000u) * 1.1920929e-7f;
        bool  flag = (s2 - s1) < (2.0f * ue + 2e-6f);
        rwin[l31]  = wi;
        rdist[l31] = s1;
        rX[l31]    = X;
        if (flag) atomicOr(&flagbits, 1u << l31);
        out[(size_t)NROWS*DIM + R0 + l31] = (float)wi;
    }
    __syncthreads();

    // ---- rescan flagged rows (np-f32 exact; block-parallel, 4 embeds/thread) ----
    unsigned bits = flagbits;
    const float* yn = (const float*)(ws + WS_YNORM);
    while (bits) {
        int r = __ffs(bits) - 1;
        bits &= bits - 1;
        if (tid < 16)
            *(float4*)(zs + tid*4) = *(const float4*)(z + (size_t)(R0 + r) * DIM + tid*4);
        __syncthreads();
        float rc[8];
        #pragma unroll
        for (int j = 0; j < 8; ++j) rc[j] = __fmul_rn(zs[j], zs[j]);
        #pragma unroll
        for (int i = 8; i < 64; i += 8)
            #pragma unroll
            for (int j = 0; j < 8; ++j)
                rc[j] = __fadd_rn(rc[j], __fmul_rn(zs[i+j], zs[i+j]));
        float xn = __fadd_rn(__fadd_rn(__fadd_rn(rc[0],rc[1]),__fadd_rn(rc[2],rc[3])),
                             __fadd_rn(__fadd_rn(rc[4],rc[5]),__fadd_rn(rc[6],rc[7])));
        float bd = 3.4e38f; int bi = NE;
        #pragma unroll
        for (int k = 0; k < 4; ++k) {
            int e = tid + 128 * k;
            const float* ep = ew + (size_t)e * DIM;
            double m0 = 0.0, m1 = 0.0, m2 = 0.0, m3 = 0.0;
            #pragma unroll
            for (int q = 0; q < 16; ++q) {
                float4 ev = *(const float4*)(ep + q*4);
                m0 = fma((double)zs[q*4+0], (double)ev.x, m0);
                m1 = fma((double)zs[q*4+1], (double)ev.y, m1);
                m2 = fma((double)zs[q*4+2], (double)ev.z, m2);
                m3 = fma((double)zs[q*4+3], (double)ev.w, m3);
            }
            double m = (m0 + m1) + (m2 + m3);
            float W = __fadd_rn(xn, yn[e]);
            float d = __fadd_rn(W, -(2.0f * (float)m));
            if (d < bd || (d == bd && e < bi)) { bd = d; bi = e; }
        }
        #pragma unroll
        for (int off = 32; off >= 1; off >>= 1) {
            float od = __shfl_xor(bd, off, 64);
            int   oi = __shfl_xor(bi, off, 64);
            if (od < bd || (od == bd && oi < bi)) { bd = od; bi = oi; }
        }
        if (lane == 0) { rd2[wv] = bd; ri2[wv] = bi; }
        __syncthreads();
        if (tid == 0) {
            float fd = rd2[0]; int fi = ri2[0];
            if (rd2[1] < fd || (rd2[1] == fd && ri2[1] < fi)) { fd = rd2[1]; fi = ri2[1]; }
            rwin[r]  = fi;
            rdist[r] = fd;     // full np distance (includes X)
            rX[r]    = 0.f;    // no double count
            out[(size_t)NROWS*DIM + R0 + r] = (float)fi;
        }
        __syncthreads();
    }

    // ---- z_q write: 32 rows x 16 float4 = 512 float4 over 128 threads ----
    #pragma unroll
    for (int i = 0; i < 4; ++i) {
        int f4  = tid + 128 * i;          // 0..511
        int row = f4 >> 4;                // 0..31
        int c4  = f4 & 15;
        float4 v = *(const float4*)(ew + (size_t)rwin[row] * DIM + c4 * 4);
        *(float4*)(out + (size_t)R0 * DIM + (size_t)f4 * 4) = v;
    }

    // ---- loss: term = X + d per row; fixed-point u64 atomic + ticket ----
    float term = (tid < 32) ? (rX[tid] + rdist[tid]) : 0.f;
    #pragma unroll
    for (int off = 32; off >= 1; off >>= 1) term += __shfl_xor(term, off, 64);
    if (tid == 0) {
        unsigned long long q =
            (unsigned long long)((double)term * 268435456.0 + 0.5);
        atomicAdd((unsigned long long*)(ws + WS_ACC), q);
        __threadfence();
        unsigned int tk = atomicAdd((unsigned int*)(ws + WS_TICKET), 1u);
        if (tk == 2047u) {
            unsigned long long tot =
                atomicAdd((unsigned long long*)(ws + WS_ACC), 0ull);
            out[(size_t)NROWS*DIM + NROWS] =
                (float)(0.25 * ((double)tot / 268435456.0)
                        / (double)((size_t)NROWS * DIM));
        }
    }
}

extern "C" void kernel_launch(void* const* d_in, const int* in_sizes, int n_in,
                              void* d_out, int out_size, void* d_ws, size_t ws_size,
                              hipStream_t stream) {
    const float* z  = (const float*)d_in[0];
    const float* ew = (const float*)d_in[1];
    float* out = (float*)d_out;
    char*  ws  = (char*)d_ws;    // ~142 KB used; every byte rewritten each call
    vq_prep <<<2,    256, 0, stream>>>(ew, ws);
    vq_fused<<<2048, 128, 0, stream>>>(z, ew, ws, out);
}

// Round 15
// 53.794 us; speedup vs baseline: 4.5071x; 3.7750x over previous
//
#include <hip/hip_runtime.h>

#define NROWS 65536
#define DIM   64
#define NE    512

// d_out is FLOAT32: [ z_q (4194304) | indices-as-float (65536) | loss (1) ]
// Scratch in d_ws (~139 KB used):
#define WS_PRESPLIT 0        // 512 rows x 256B: (-2e)_hi XOR-swizzled | (-2e)_lo at +128
#define WS_PREY     131072   // 512 x 16B: (ynorm_hi, ynorm_lo, 0...)
#define WS_YNORM    139264   // 512 x f32 np-pairwise ||e||^2
#define WS_ACC      141312   // u64 fixed-point loss accumulator
#define WS_TICKET   141320   // u32 completion ticket

typedef __attribute__((ext_vector_type(8)))  short bf16x8;
typedef __attribute__((ext_vector_type(16))) float f32x16;

static __device__ __forceinline__ unsigned short bf16rne(float x) {
    unsigned int u = __float_as_uint(x);
    u += 0x7FFFu + ((u >> 16) & 1u);            // RNE (finite inputs only)
    return (unsigned short)(u >> 16);
}
static __device__ __forceinline__ float bf16tof(unsigned short h) {
    return __uint_as_float(((unsigned int)h) << 16);
}

// K0: codebook prep (512 rows, 2 blocks), swizzle baked; zero acc/ticket.
__global__ __launch_bounds__(256) void vq_prep(
    const float* __restrict__ ew, char* ws)
{
    const int r = blockIdx.x * 256 + threadIdx.x;     // 0..511
    if (r == 0) {
        *(unsigned long long*)(ws + WS_ACC)    = 0ull;
        *(unsigned long long*)(ws + WS_TICKET) = 0ull;
    }
    float a[64];
    const float4* src = (const float4*)(ew + (size_t)r * DIM);
    #pragma unroll
    for (int q = 0; q < 16; ++q) {
        float4 v = src[q];
        a[q*4+0]=v.x; a[q*4+1]=v.y; a[q*4+2]=v.z; a[q*4+3]=v.w;
    }
    // numpy-pairwise ||e||^2 (exact np f32 order)
    float rc[8];
    #pragma unroll
    for (int j = 0; j < 8; ++j) rc[j] = __fmul_rn(a[j], a[j]);
    #pragma unroll
    for (int i = 8; i < 64; i += 8)
        #pragma unroll
        for (int j = 0; j < 8; ++j)
            rc[j] = __fadd_rn(rc[j], __fmul_rn(a[i+j], a[i+j]));
    float Y = __fadd_rn(__fadd_rn(__fadd_rn(rc[0],rc[1]),__fadd_rn(rc[2],rc[3])),
                        __fadd_rn(__fadd_rn(rc[4],rc[5]),__fadd_rn(rc[6],rc[7])));
    ((float*)(ws + WS_YNORM))[r] = Y;
    unsigned short ynh = bf16rne(Y);
    unsigned short ynl = bf16rne(Y - bf16tof(ynh));
    bf16x8 py = {};
    py[0] = (short)ynh; py[1] = (short)ynl;
    *(bf16x8*)(ws + WS_PREY + r*16) = py;
    const int sw = (r & 7) << 4;
    char* base = ws + WS_PRESPLIT + (size_t)r * 256;
    #pragma unroll
    for (int c = 0; c < 8; ++c) {
        bf16x8 h, l;
        #pragma unroll
        for (int j = 0; j < 8; ++j) {
            float x = -2.0f * a[c*8+j];
            unsigned short hb = bf16rne(x);
            h[j] = (short)hb;
            l[j] = (short)bf16rne(x - bf16tof(hb));
        }
        int off = (c*16) ^ sw;
        *(bf16x8*)(base + off)       = h;
        *(bf16x8*)(base + off + 128) = l;
    }
}

// K1: 256 blocks x 1024 threads (16 waves, 1 block/CU, 4 waves/SIMD).
// Block owns 256 z-rows. Wave wv: row-group rg=wv>>1 (32 rows), embed half
// eh=wv&1. Full split codebook staged once into LDS; MFMA ranking; pair merge;
// in-block rescan of flagged rows; z_q/index/loss epilogue.
__global__ __launch_bounds__(1024) void vq_fused(
    const float* __restrict__ z, const float* __restrict__ ew,
    char* ws, float* out)
{
    __shared__ __align__(16) char ldsA[131072];   // preSplit (swizzled)
    __shared__ __align__(16) char ldsY[8192];     // preY fragments
    __shared__ float4 mrg[8][32];
    __shared__ int    rwin[256];
    __shared__ float  rdist[256];
    __shared__ float  rX[256];
    __shared__ float  zs[64];
    __shared__ float  rd8[8];
    __shared__ int    ri8[8];
    __shared__ unsigned int flagbits[8];
    __shared__ float  wred[4];

    const int tid  = threadIdx.x;
    const int lane = tid & 63;
    const int wv   = tid >> 6;       // 0..15
    const int rg   = wv >> 1;        // 0..7 row group
    const int eh   = wv & 1;         // embed half
    const int hh   = lane >> 5;
    const int l31  = lane & 31;
    const int R0   = blockIdx.x * 256;
    const int zrow = R0 + rg*32 + l31;
    const int eoff = eh * 256;

    if (tid < 8) flagbits[tid] = 0u;

    // ---- z fragments (split-bf16) + f32 sum-sq; B: n=lane&31, k=8*hh+j ----
    bf16x8 zh[4], zl[4];
    float xacc = 0.f;
    {
        const float* zp = z + (size_t)zrow * DIM + hh * 8;
        #pragma unroll
        for (int kt = 0; kt < 4; ++kt) {
            float4 p0 = *(const float4*)(zp + kt*16);
            float4 p1 = *(const float4*)(zp + kt*16 + 4);
            float a[8] = {p0.x,p0.y,p0.z,p0.w,p1.x,p1.y,p1.z,p1.w};
            bf16x8 hv, lv;
            #pragma unroll
            for (int j = 0; j < 8; ++j) {
                unsigned short hb = bf16rne(a[j]);
                hv[j] = (short)hb;
                lv[j] = (short)bf16rne(a[j] - bf16tof(hb));
                xacc  = fmaf(a[j], a[j], xacc);
            }
            zh[kt] = hv; zl[kt] = lv;
        }
    }

    // ---- stage preSplit+preY (139264 B = 8704 x 16B chunks), register-lean ----
    #pragma unroll 1
    for (int i = 0; i < 9; ++i) {
        int idx = tid + 1024 * i;
        if (idx < 8704) {
            float4 v = *(const float4*)(ws + idx*16);
            if (idx < 8192) *(float4*)(ldsA + idx*16) = v;
            else            *(float4*)(ldsY + (idx - 8192)*16) = v;
        }
    }
    __syncthreads();

    const bf16x8 zero8 = {};
    bf16x8 bones = {};
    if (hh == 0) { bones[0] = (short)0x3F80; bones[1] = (short)0x3F80; }

    float d1 = 3.4e38f, d2 = 3.4e38f;
    int   i1 = 0;

    // ---- main loop: 8 tiles of 32 embeds (this wave's half); barrier-free ----
    #pragma unroll 1
    for (int t = 0; t < 8; ++t) {
        const int   e0    = eoff + t*32;
        const int   arow  = e0 + l31;
        const char* abase = ldsA + arow*256;
        const int   sw    = (arow & 7) << 4;

        f32x16 acc;
        #pragma unroll
        for (int g = 0; g < 16; ++g) acc[g] = 0.f;

        bf16x8 ay = zero8;
        if (hh == 0) ay = *(const bf16x8*)(ldsY + arow*16);
        acc = __builtin_amdgcn_mfma_f32_32x32x16_bf16(ay, bones, acc, 0,0,0);

        #pragma unroll
        for (int kt = 0; kt < 4; ++kt) {
            const int kb = (kt*32 + hh*16) ^ sw;
            bf16x8 ah = *(const bf16x8*)(abase + kb);
            bf16x8 al = *(const bf16x8*)(abase + kb + 128);
            acc = __builtin_amdgcn_mfma_f32_32x32x16_bf16(ah, zh[kt], acc, 0,0,0);
            acc = __builtin_amdgcn_mfma_f32_32x32x16_bf16(ah, zl[kt], acc, 0,0,0);
            acc = __builtin_amdgcn_mfma_f32_32x32x16_bf16(al, zh[kt], acc, 0,0,0);
        }

        const int ebase = e0 + 4*hh;
        #pragma unroll
        for (int g = 0; g < 16; ++g) {
            float d = acc[g];                 // ynorm[e] - 2 z.e (approx)
            int   e = ebase + (g & 3) + 8*(g >> 2);
            d2 = fminf(fmaxf(d, d1), d2);
            bool bt = d < d1;
            i1 = bt ? e : i1;
            d1 = fminf(d, d1);
        }
    }

    // ---- intra-wave hh merge ----
    float od1 = __shfl_xor(d1, 32, 64);
    int   oi1 = __shfl_xor(i1, 32, 64);
    float od2 = __shfl_xor(d2, 32, 64);
    bool  oth = (od1 < d1) || (od1 == d1 && oi1 < i1);
    int   wiw = oth ? oi1 : i1;
    float s1w = fminf(d1, od1);
    float s2w = fminf(fmaxf(d1, od1), fminf(d2, od2));
    float X   = xacc + __shfl_xor(xacc, 32, 64);

    // ---- pair merge (eh=0 wave finalizes; its indices are lower on ties) ----
    if (eh == 1 && hh == 0)
        mrg[rg][l31] = make_float4(s1w, __int_as_float(wiw), s2w, 0.f);
    __syncthreads();
    if (eh == 0 && hh == 0) {
        float4 b = mrg[rg][l31];
        float s1b = b.x, s2b = b.z;
        int   ib  = __float_as_int(b.y);
        bool  tA  = (s1w <= s1b);
        int   wi  = tA ? wiw : ib;
        float s1  = fminf(s1w, s1b);
        float s2  = fminf(fmaxf(s1w, s1b), fminf(s2w, s2b));
        float Xs  = X + 1e-3f;
        float ue  = __uint_as_float(__float_as_uint(Xs) & 0x7F800000u) * 1.1920929e-7f;
        bool  flag = (s2 - s1) < (2.0f * ue + 2e-6f);
        int r = rg*32 + l31;
        rwin[r]  = wi;
        rdist[r] = s1;
        rX[r]    = X;
        if (flag) atomicOr(&flagbits[rg], 1u << l31);
    }
    __syncthreads();

    // ---- rescan flagged rows (np-f32 exact; 512 threads, 1 embed each) ----
    const float* yn = (const float*)(ws + WS_YNORM);
    for (int g8 = 0; g8 < 8; ++g8) {
        unsigned bits = flagbits[g8];
        while (bits) {
            int r = g8*32 + __ffs(bits) - 1;
            bits &= bits - 1;
            if (tid < 16)
                *(float4*)(zs + tid*4) =
                    *(const float4*)(z + (size_t)(R0 + r) * DIM + tid*4);
            __syncthreads();
            float rc[8];
            #pragma unroll
            for (int j = 0; j < 8; ++j) rc[j] = __fmul_rn(zs[j], zs[j]);
            #pragma unroll
            for (int i = 8; i < 64; i += 8)
                #pragma unroll
                for (int j = 0; j < 8; ++j)
                    rc[j] = __fadd_rn(rc[j], __fmul_rn(zs[i+j], zs[i+j]));
            float xn = __fadd_rn(__fadd_rn(__fadd_rn(rc[0],rc[1]),__fadd_rn(rc[2],rc[3])),
                                 __fadd_rn(__fadd_rn(rc[4],rc[5]),__fadd_rn(rc[6],rc[7])));
            float bd = 3.4e38f; int bi = NE;
            if (tid < NE) {
                const int e = tid;
                const float* ep = ew + (size_t)e * DIM;
                double m0 = 0.0, m1 = 0.0, m2 = 0.0, m3 = 0.0;
                #pragma unroll
                for (int q = 0; q < 16; ++q) {
                    float4 ev = *(const float4*)(ep + q*4);
                    m0 = fma((double)zs[q*4+0], (double)ev.x, m0);
                    m1 = fma((double)zs[q*4+1], (double)ev.y, m1);
                    m2 = fma((double)zs[q*4+2], (double)ev.z, m2);
                    m3 = fma((double)zs[q*4+3], (double)ev.w, m3);
                }
                double m = (m0 + m1) + (m2 + m3);
                float W = __fadd_rn(xn, yn[e]);
                float d = __fadd_rn(W, -(2.0f * (float)m));
                bd = d; bi = e;
            }
            #pragma unroll
            for (int off = 32; off >= 1; off >>= 1) {
                float od = __shfl_xor(bd, off, 64);
                int   oi = __shfl_xor(bi, off, 64);
                if (od < bd || (od == bd && oi < bi)) { bd = od; bi = oi; }
            }
            if (lane == 0 && wv < 8) { rd8[wv] = bd; ri8[wv] = bi; }
            __syncthreads();
            if (tid == 0) {
                float fd = rd8[0]; int fi = ri8[0];
                #pragma unroll
                for (int k = 1; k < 8; ++k)
                    if (rd8[k] < fd || (rd8[k] == fd && ri8[k] < fi)) { fd = rd8[k]; fi = ri8[k]; }
                rwin[r]  = fi;
                rdist[r] = fd;     // full np distance (includes X)
                rX[r]    = 0.f;    // no double count in loss
            }
            __syncthreads();
        }
    }

    // ---- index write (coalesced 256 floats) ----
    if (tid < 256)
        out[(size_t)NROWS*DIM + R0 + tid] = (float)rwin[tid];

    // ---- z_q write: 256 rows x 16 float4 = 4096 float4 over 1024 threads ----
    #pragma unroll
    for (int i = 0; i < 4; ++i) {
        int f4  = tid + 1024 * i;         // 0..4095
        int row = f4 >> 4;                // 0..255
        int c4  = f4 & 15;
        float4 v = *(const float4*)(ew + (size_t)rwin[row] * DIM + c4 * 4);
        *(float4*)(out + (size_t)R0 * DIM + (size_t)f4 * 4) = v;
    }

    // ---- loss: term = X + d per row; fixed-point u64 atomic + ticket ----
    float term = (tid < 256) ? (rX[tid] + rdist[tid]) : 0.f;
    #pragma unroll
    for (int off = 32; off >= 1; off >>= 1) term += __shfl_xor(term, off, 64);
    if (lane == 0 && wv < 4) wred[wv] = term;
    __syncthreads();
    if (tid == 0) {
        float part = wred[0] + wred[1] + wred[2] + wred[3];
        unsigned long long q =
            (unsigned long long)((double)part * 268435456.0 + 0.5);
        atomicAdd((unsigned long long*)(ws + WS_ACC), q);
        __threadfence();
        unsigned int tk = atomicAdd((unsigned int*)(ws + WS_TICKET), 1u);
        if (tk == 255u) {
            unsigned long long tot =
                atomicAdd((unsigned long long*)(ws + WS_ACC), 0ull);
            out[(size_t)NROWS*DIM + NROWS] =
                (float)(0.25 * ((double)tot / 268435456.0)
                        / (double)((size_t)NROWS * DIM));
        }
    }
}

extern "C" void kernel_launch(void* const* d_in, const int* in_sizes, int n_in,
                              void* d_out, int out_size, void* d_ws, size_t ws_size,
                              hipStream_t stream) {
    const float* z  = (const float*)d_in[0];
    const float* ew = (const float*)d_in[1];
    float* out = (float*)d_out;
    char*  ws  = (char*)d_ws;    // ~139 KB used; every byte rewritten each call
    vq_prep <<<2,   256,  0, stream>>>(ew, ws);
    vq_fused<<<256, 1024, 0, stream>>>(z, ew, ws, out);
}